// Round 8
// baseline (10837.066 us; speedup 1.0000x reference)
//
#include <hip/hip_runtime.h>
#include <cstdint>
#include <cstddef>

#define BB 32
#define NN 256
#define PP 3072
#define NG 192
#define RING 16

#define MAGICI 0x1357A001
#define MAGICW 0x1357B002
#define MAGICR 0x1357C003
#define MAGICG 0x1357D000  // + k2 (0..39)
#define MAGICM 0x1357E000  // + k2 (1..39)
#define MAGICC 0x1357F004

typedef unsigned short u16;

__device__ __forceinline__ void spin_eq(int* f, int want) {
  for (long it = 0; it < 200000000L; ++it) {  // bounded: fail, never hang
    if (__hip_atomic_load(f, __ATOMIC_ACQUIRE, __HIP_MEMORY_SCOPE_AGENT) ==
        want)
      return;
    __builtin_amdgcn_s_sleep(1);
  }
}

// 224 blocks: blk 0..191 spike role (b=blk/6, sub=blk%6, px sub*512..+511),
// blk 192..223 theta role (b=blk-192). Per-batch producer/consumer flags;
// no grid-wide sync. Membrane/spikes/rate in spike-thread registers.
__global__ __launch_bounds__(512) void k_persist(
    const float* __restrict__ x, const float* __restrict__ theta0,
    const float* __restrict__ W_init, const float* __restrict__ omega,
    const float* __restrict__ W_ro, const float* __restrict__ W_gate,
    const float* __restrict__ W_rec, const float* __restrict__ W_fb,
    const float* __restrict__ W_cls, const float* __restrict__ bcls,
    float* __restrict__ out, double* __restrict__ gpartI,
    double* __restrict__ gateG, u16* __restrict__ listG,
    int* __restrict__ cntG, float* __restrict__ WgT, float* __restrict__ WroT,
    double* __restrict__ clsP, u16* __restrict__ maskG,
    int* __restrict__ flags) {
  __shared__ double smem[6144];  // 48 KB, role-dependent carve
  const int blk = blockIdx.x, tid = threadIdx.x, lane = tid & 63;
  int* initF = flags;          // [32*8]
  int* wgF = flags + 256;      // [8]
  int* wroF = flags + 264;     // [1]
  int* gateF = flags + 272;    // [32]
  int* maskF = flags + 304;    // [32*8]
  int* clsF = flags + 560;     // [32*8]

  if (blk < NG) {
    // ==================== SPIKE ROLE ====================
    const int b = blk / 6, sub = blk % 6;
    const int p = sub * 512 + tid;
    double* gd = smem;                            // 256 dbl
    u16* list_s = (u16*)(smem + 512);             // 3072 u16
    int* cnt_s = (int*)(smem + 1280);

    // ---- init partial: gamma0 chunk (K rows sub*512..+511) ----
    {
      smem[tid] = (double)x[(size_t)b * PP + p];
      __syncthreads();
      const int osc = tid & 255, kh = tid >> 8;
      const float* wp = W_init + (size_t)(sub * 512 + kh * 256) * NN + osc;
      const double* xp = smem + kh * 256;
      double a0 = 0, a1 = 0, a2 = 0, a3 = 0, a4 = 0, a5 = 0, a6 = 0, a7 = 0;
      for (int r = 0; r < 256; r += 8) {
        a0 += xp[r + 0] * (double)wp[(size_t)(r + 0) * NN];
        a1 += xp[r + 1] * (double)wp[(size_t)(r + 1) * NN];
        a2 += xp[r + 2] * (double)wp[(size_t)(r + 2) * NN];
        a3 += xp[r + 3] * (double)wp[(size_t)(r + 3) * NN];
        a4 += xp[r + 4] * (double)wp[(size_t)(r + 4) * NN];
        a5 += xp[r + 5] * (double)wp[(size_t)(r + 5) * NN];
        a6 += xp[r + 6] * (double)wp[(size_t)(r + 6) * NN];
        a7 += xp[r + 7] * (double)wp[(size_t)(r + 7) * NN];
      }
      double acc = ((a0 + a1) + (a2 + a3)) + ((a4 + a5) + (a6 + a7));
      __syncthreads();
      if (kh) smem[osc] = acc;
      __syncthreads();
      if (!kh) gpartI[((size_t)b * 6 + sub) * 256 + osc] = acc + smem[osc];
      __threadfence();
      __syncthreads();
      if (tid == 0)
        __hip_atomic_store(initF + b * 8 + sub, MAGICI, __ATOMIC_RELEASE,
                           __HIP_MEMORY_SCOPE_AGENT);
    }
    // ---- one-time transposes (b==0 blocks: W_gate chunk; blk==6: W_ro) ----
    if (b == 0) {
      const int pp2 = sub * 512 + tid;
#pragma unroll 8
      for (int k = 0; k < 256; ++k)
        WgT[(size_t)pp2 * 256 + k] = W_gate[(size_t)k * PP + pp2];
      __threadfence();
      __syncthreads();
      if (tid == 0)
        __hip_atomic_store(wgF + sub, MAGICW, __ATOMIC_RELEASE,
                           __HIP_MEMORY_SCOPE_AGENT);
    }
    if (blk == 6) {
      if (tid < 256) {
#pragma unroll 8
        for (int i = 0; i < 256; ++i)
          WroT[(size_t)tid * 256 + i] = W_ro[(size_t)i * 256 + tid];
      }
      __threadfence();
      __syncthreads();
      if (tid == 0)
        __hip_atomic_store(wroF, MAGICR, __ATOMIC_RELEASE,
                           __HIP_MEMORY_SCOPE_AGENT);
    }
    // wait for this block's W_gate chunk transpose
    if (tid == 0) spin_eq(wgF + sub, MAGICW);
    __syncthreads();

    // ---- persistent per-thread state (one pixel per thread) ----
    double mem_reg = 0.0, prev_s = 0.0;
    int rate_cnt = 0;

    for (int k2 = 1; k2 <= 39; ++k2) {
      if (tid == 0) spin_eq(gateF + b, MAGICG + (k2 - 1));
      __syncthreads();
      if (tid < 256) gd[tid] = gateG[b * 256 + tid];
      if (tid == 0) cnt_s[0] = cntG[b];
      __syncthreads();
      const int cnt = cnt_s[0];
      for (int i = tid; i < cnt; i += 512) list_s[i] = listG[b * PP + i];
      __syncthreads();

      // gate dot: K=256 fp64, gate in LDS (broadcast), W_gate^T contiguous
      double s0 = 0, s1 = 0, s2 = 0, s3 = 0, s4 = 0, s5 = 0, s6 = 0, s7 = 0;
      const float4* wgp = (const float4*)(WgT + (size_t)p * 256);
#pragma unroll 4
      for (int q = 0; q < 64; q += 2) {
        float4 wa = wgp[q], wb2 = wgp[q + 1];
        const double* gq = gd + q * 4;
        s0 += gq[0] * (double)wa.x;
        s1 += gq[1] * (double)wa.y;
        s2 += gq[2] * (double)wa.z;
        s3 += gq[3] * (double)wa.w;
        s4 += gq[4] * (double)wb2.x;
        s5 += gq[5] * (double)wb2.y;
        s6 += gq[6] * (double)wb2.z;
        s7 += gq[7] * (double)wb2.w;
      }
      const double vg = ((s0 + s1) + (s2 + s3)) + ((s4 + s5) + (s6 + s7));

      // rec: sparse sum over active-pixel list (8 independent streams)
      double v0 = 0, v1 = 0, v2 = 0, v3 = 0, v4 = 0, v5 = 0, v6 = 0, v7 = 0;
      int i = 0;
      for (; i + 8 <= cnt; i += 8) {
        const int r0 = list_s[i], r1 = list_s[i + 1], r2 = list_s[i + 2],
                  r3 = list_s[i + 3], r4 = list_s[i + 4], r5 = list_s[i + 5],
                  r6 = list_s[i + 6], r7 = list_s[i + 7];
        v0 += (double)W_rec[(size_t)r0 * PP + p];
        v1 += (double)W_rec[(size_t)r1 * PP + p];
        v2 += (double)W_rec[(size_t)r2 * PP + p];
        v3 += (double)W_rec[(size_t)r3 * PP + p];
        v4 += (double)W_rec[(size_t)r4 * PP + p];
        v5 += (double)W_rec[(size_t)r5 * PP + p];
        v6 += (double)W_rec[(size_t)r6 * PP + p];
        v7 += (double)W_rec[(size_t)r7 * PP + p];
      }
      double vr = ((v0 + v1) + (v2 + v3)) + ((v4 + v5) + (v6 + v7));
      for (; i < cnt; ++i) vr += (double)W_rec[(size_t)list_s[i] * PP + p];

      const double cur = vg + 0.1 * vr;
      const double mv = 0.9 * mem_reg * (1.0 - prev_s) + cur;
      const double sv = (mv - 1.0 > 0.0) ? 1.0 : 0.0;
      mem_reg = mv;
      if (k2 >= 10) rate_cnt += (int)sv;
      prev_s = sv;
      unsigned long long bal = __ballot(sv > 0.5);
      if ((lane & 15) == 0)
        maskG[b * NG + (p >> 4)] =
            (u16)((bal >> (16 * (lane >> 4))) & 0xFFFFull);
      __threadfence();
      __syncthreads();
      if (tid == 0)
        __hip_atomic_store(maskF + b * 8 + sub, MAGICM + k2, __ATOMIC_RELEASE,
                           __HIP_MEMORY_SCOPE_AGENT);
    }

    // ---- classifier partial: (rate/30) @ W_cls over this block's pixels ----
    __syncthreads();
    {
      const double rv = (double)rate_cnt / 30.0;
      double part[10];
#pragma unroll
      for (int c = 0; c < 10; ++c)
        part[c] = rv * (double)W_cls[(size_t)p * 10 + c];
#pragma unroll
      for (int c = 0; c < 10; ++c) smem[c * 512 + tid] = part[c];
      __syncthreads();
      for (int off = 256; off; off >>= 1) {
        if (tid < off)
#pragma unroll
          for (int c = 0; c < 10; ++c)
            smem[c * 512 + tid] += smem[c * 512 + tid + off];
        __syncthreads();
      }
      if (tid < 10)
        clsP[((size_t)b * 6 + sub) * 10 + tid] = smem[tid * 512];
      __threadfence();
      __syncthreads();
      if (tid == 0)
        __hip_atomic_store(clsF + b * 8 + sub, MAGICC, __ATOMIC_RELEASE,
                           __HIP_MEMORY_SCOPE_AGENT);
    }
  } else {
    // ==================== THETA ROLE ====================
    const int b = blk - NG;
    const int j = tid & 255, half = tid >> 8, wid = tid >> 6;
    double* ring = smem;                                // 4096 dbl
    double* th = smem + 4096;                           // 256
    double* red = smem + 4352;                          // 32
    double* ahalf = smem + 4384;                        // 256
    int* pc = (int*)(smem + 4640);                      // 192
    int* sc = pc + NG;                                  // 192
    u16* m_l = (u16*)(sc + NG);                         // 192
    u16* list_l = m_l + NG;                             // 3072

    // gamma0 from init partials
    if (tid < 6) spin_eq(initF + b * 8 + tid, MAGICI);
    __syncthreads();
    double t = 0.0, aj = 0.0, gm = 0.0, om = 0.0;
    if (tid < 256) {
      double s = 0.0;
      for (int c6 = 0; c6 < 6; ++c6)
        s += gpartI[((size_t)b * 6 + c6) * 256 + j];
      gm = tanh(s);
      t = (double)theta0[b * NN + j];
      om = (double)omega[j];
      ring[0 * NN + j] = t;
    }
    __syncthreads();

    for (int k2 = 0; k2 <= 39; ++k2) {
      double new_a = 0.0;
      int total = 0;
      if (k2 > 0) {
        if (tid < 6) spin_eq(maskF + b * 8 + tid, MAGICM + k2);
        __syncthreads();
        // compact spike mask -> sorted pixel list
        if (tid < NG) {
          m_l[tid] = maskG[b * NG + tid];
          pc[tid] = __popc((unsigned int)m_l[tid]);
          sc[tid] = pc[tid];
        }
        __syncthreads();
        for (int d = 1; d < NG; d <<= 1) {
          int v = 0;
          if (tid < NG) v = sc[tid] + ((tid >= d) ? sc[tid - d] : 0);
          __syncthreads();
          if (tid < NG) sc[tid] = v;
          __syncthreads();
        }
        total = sc[NG - 1];
        if (tid < NG) {
          int off = sc[tid] - pc[tid];
          unsigned int m = m_l[tid];
          while (m) {
            int bit = __builtin_ctz(m);
            m &= m - 1;
            list_l[off++] = (u16)(tid * 16 + bit);
          }
        }
        __syncthreads();
        for (int i = tid; i < total; i += 512) listG[b * PP + i] = list_l[i];
        if (tid == 0) cntG[b] = total;
        // a = tanh(spk @ W_fb): 8 streams over the compact list
        double c0 = 0, c1 = 0, c2 = 0, c3 = 0, c4 = 0, c5 = 0, c6 = 0, c7 = 0;
        int i = half;
        for (; i + 16 <= total; i += 16) {
          c0 += (double)W_fb[(size_t)list_l[i + 0] * NN + j];
          c1 += (double)W_fb[(size_t)list_l[i + 2] * NN + j];
          c2 += (double)W_fb[(size_t)list_l[i + 4] * NN + j];
          c3 += (double)W_fb[(size_t)list_l[i + 6] * NN + j];
          c4 += (double)W_fb[(size_t)list_l[i + 8] * NN + j];
          c5 += (double)W_fb[(size_t)list_l[i + 10] * NN + j];
          c6 += (double)W_fb[(size_t)list_l[i + 12] * NN + j];
          c7 += (double)W_fb[(size_t)list_l[i + 14] * NN + j];
        }
        double acc = ((c0 + c1) + (c2 + c3)) + ((c4 + c5) + (c6 + c7));
        for (; i < total; i += 2) acc += (double)W_fb[(size_t)list_l[i] * NN + j];
        if (half) ahalf[j] = acc;
        __syncthreads();
        if (!half) new_a = tanh(acc + ahalf[j]);
      } else {
        if (tid == 0) cntG[b] = 0;
      }

      const int s0 = 5 * k2 + 1, s1 = 5 * k2 + 5;
      for (int s = s0; s <= s1; ++s) {
        if (tid < 256 && k2 > 0 && s == s0 + 1) aj = new_a;  // s0 uses OLD a
        double sn = 0.0, cs = 0.0;
        if (tid < 256) sincos(t, &sn, &cs);
        double r0 = sn, r1 = cs, r2 = aj * sn, r3 = aj * cs;
#pragma unroll
        for (int o = 32; o; o >>= 1) {
          r0 += __shfl_down(r0, o);
          r1 += __shfl_down(r1, o);
          r2 += __shfl_down(r2, o);
          r3 += __shfl_down(r3, o);
        }
        if (lane == 0) {
          red[wid * 4 + 0] = r0;
          red[wid * 4 + 1] = r1;
          red[wid * 4 + 2] = r2;
          red[wid * 4 + 3] = r3;
        }
        __syncthreads();
        double S = red[0] + red[4] + red[8] + red[12];
        double C = red[1] + red[5] + red[9] + red[13];
        double AS = red[2] + red[6] + red[10] + red[14];
        double AC = red[3] + red[7] + red[11] + red[15];
        __syncthreads();
        if (tid < 256) {
          double base = cs * S - sn * C;
          double wgt = 0.5 * (cs * aj * AS - sn * aj * AC);
          t = t + 0.1 * (om + (1.0 / 256.0) * (base + wgt) + 0.5 * gm);
          ring[(s & (RING - 1)) * NN + j] = t;
        }
      }
      if (tid < 256) th[j] = t;
      __syncthreads();
      if (k2 == 0) {
        if (tid == 0) spin_eq(wroF, MAGICR);
        __syncthreads();
      }
      if (tid < 256) {
        // gamma = tanh(theta @ W_ro) via W_ro^T contiguous, 8 streams
        double c0 = 0, c1 = 0, c2 = 0, c3 = 0, c4 = 0, c5 = 0, c6 = 0, c7 = 0;
        const float4* wp = (const float4*)(WroT + (size_t)j * 256);
#pragma unroll 4
        for (int q = 0; q < 64; q += 2) {
          float4 wa = wp[q], wb2 = wp[q + 1];
          const double* tq = th + q * 4;
          c0 += tq[0] * (double)wa.x;
          c1 += tq[1] * (double)wa.y;
          c2 += tq[2] * (double)wa.z;
          c3 += tq[3] * (double)wa.w;
          c4 += tq[4] * (double)wb2.x;
          c5 += tq[5] * (double)wb2.y;
          c6 += tq[6] * (double)wb2.z;
          c7 += tq[7] * (double)wb2.w;
        }
        gm = tanh(((c0 + c1) + (c2 + c3)) + ((c4 + c5) + (c6 + c7)));
        int sd = s1 - 11;
        if (sd < 0) sd = 0;
        double dly = ring[(sd & (RING - 1)) * NN + j];
        double gt = gm * 0.5 * (1.0 + cos(t - dly));
        gateG[b * 256 + j] = gt;
      }
      __threadfence();
      __syncthreads();
      if (tid == 0)
        __hip_atomic_store(gateF + b, MAGICG + k2, __ATOMIC_RELEASE,
                           __HIP_MEMORY_SCOPE_AGENT);
    }

    // ---- final: reduce classifier partials, write logits ----
    if (tid < 6) spin_eq(clsF + b * 8 + tid, MAGICC);
    __syncthreads();
    if (tid < 10) {
      double s = (double)bcls[tid];
      for (int i = 0; i < 6; ++i) s += clsP[((size_t)b * 6 + i) * 10 + tid];
      out[b * 10 + tid] = (float)s;
    }
  }
}

extern "C" void kernel_launch(void* const* d_in, const int* in_sizes, int n_in,
                              void* d_out, int out_size, void* d_ws,
                              size_t ws_size, hipStream_t stream) {
  const float* x = (const float*)d_in[0];
  const float* theta0 = (const float*)d_in[1];
  const float* W_init = (const float*)d_in[2];
  const float* omega = (const float*)d_in[3];
  const float* W_ro = (const float*)d_in[4];
  const float* W_gate = (const float*)d_in[5];
  const float* W_rec = (const float*)d_in[6];
  const float* W_fb = (const float*)d_in[7];
  const float* W_cls = (const float*)d_in[8];
  const float* b_cls = (const float*)d_in[9];
  float* outp = (float*)d_out;

  char* w = (char*)d_ws;
  size_t off = 0;
  auto alloc = [&](size_t sz) -> void* {
    void* p = w + off;
    off = (off + sz + 255) & ~(size_t)255;
    return p;
  };
  double* gpartI = (double*)alloc((size_t)BB * 6 * 256 * 8);
  double* gateG = (double*)alloc((size_t)BB * 256 * 8);
  u16* listG = (u16*)alloc((size_t)BB * PP * 2);
  int* cntG = (int*)alloc((size_t)BB * 4);
  float* WgT = (float*)alloc((size_t)PP * 256 * 4);
  float* WroT = (float*)alloc((size_t)256 * 256 * 4);
  double* clsP = (double*)alloc((size_t)BB * 6 * 10 * 8);
  u16* maskG = (u16*)alloc((size_t)BB * NG * 2);
  int* flags = (int*)alloc((size_t)1024 * 4);
  // ~4.1 MB of ws; flags found via epoch tags (0xAA poison never matches)

  void* args[] = {&x,    &theta0, &W_init, &omega, &W_ro, &W_gate, &W_rec,
                  &W_fb, &W_cls,  &b_cls,  &outp,  &gpartI, &gateG, &listG,
                  &cntG, &WgT,    &WroT,   &clsP,  &maskG,  &flags};
  hipLaunchCooperativeKernel((void*)k_persist, dim3(224), dim3(512), args, 0,
                             stream);
}

// Round 9
// 3213.640 us; speedup vs baseline: 3.3722x; 3.3722x over previous
//
#include <hip/hip_runtime.h>
#include <cstdint>
#include <cstddef>

#define BB 32
#define NN 256
#define PP 3072
#define NG 192   // pixel groups of 16
#define RING 16

typedef unsigned short u16;

// ---- init: gamma0 partials (192 blocks) + state zeroing (32 blocks) ----
__global__ __launch_bounds__(512) void k_init(
    const float* __restrict__ x, const float* __restrict__ W_init,
    double* __restrict__ gpartI, double* __restrict__ memD,
    double* __restrict__ a_g, float* __restrict__ rate,
    u16* __restrict__ maskA, u16* __restrict__ maskB) {
  const int blk = blockIdx.x, tid = threadIdx.x;
  if (blk < 192) {
    // partial of x@W_init: batch b, K-chunk sub (512 rows)
    const int b = blk / 6, sub = blk % 6;
    __shared__ double xl[512];
    xl[tid] = (double)x[(size_t)b * PP + sub * 512 + tid];
    __syncthreads();
    const int osc = tid & 255, kh = tid >> 8;
    const float* wp = W_init + (size_t)(sub * 512 + kh * 256) * NN + osc;
    const double* xp = xl + kh * 256;
    double a0 = 0, a1 = 0, a2 = 0, a3 = 0, a4 = 0, a5 = 0, a6 = 0, a7 = 0;
    for (int r = 0; r < 256; r += 8) {
      a0 += xp[r + 0] * (double)wp[(size_t)(r + 0) * NN];
      a1 += xp[r + 1] * (double)wp[(size_t)(r + 1) * NN];
      a2 += xp[r + 2] * (double)wp[(size_t)(r + 2) * NN];
      a3 += xp[r + 3] * (double)wp[(size_t)(r + 3) * NN];
      a4 += xp[r + 4] * (double)wp[(size_t)(r + 4) * NN];
      a5 += xp[r + 5] * (double)wp[(size_t)(r + 5) * NN];
      a6 += xp[r + 6] * (double)wp[(size_t)(r + 6) * NN];
      a7 += xp[r + 7] * (double)wp[(size_t)(r + 7) * NN];
    }
    double acc = ((a0 + a1) + (a2 + a3)) + ((a4 + a5) + (a6 + a7));
    __syncthreads();
    __shared__ double hl[256];
    if (kh) hl[osc] = acc;
    __syncthreads();
    if (!kh) gpartI[((size_t)b * 6 + sub) * 256 + osc] = acc + hl[osc];
  } else {
    const int b = blk - 192;
    for (int i = tid; i < PP; i += 512) {
      memD[(size_t)b * PP + i] = 0.0;
      rate[(size_t)b * PP + i] = 0.f;
    }
    for (int i = tid; i < NG; i += 512) {
      maskA[b * NG + i] = 0;
      maskB[b * NG + i] = 0;
    }
    for (int i = tid; i < NN; i += 512) a_g[b * NN + i] = 0.0;
  }
}

// ---- spike update (s = 5k+1), fp64 VALU, 2-way K-split, 16-batch blocks ----
// grid (192 groups, 2 batch-halves), 512 thr = 16px x 16b x 2 K-halves.
__global__ __launch_bounds__(512) void k_spike(
    const u16* __restrict__ mask_rd, u16* __restrict__ mask_wr,
    double* __restrict__ memD, const double* __restrict__ gateG,
    const float* __restrict__ W_rec, const float* __restrict__ W_gate,
    const u16* __restrict__ listG, const int* __restrict__ cntG,
    float* __restrict__ rate, int accum) {
  __shared__ double gd[256 * 16];  // 32 KB: gate [k][bl] for this batch-half
  __shared__ double vgp[256], vrp[256];
  const int g = blockIdx.x, bh = blockIdx.y, j0 = g * 16;
  const int tid = threadIdx.x;
  const int pi = tid & 15, bl = (tid >> 4) & 15, h = tid >> 8;
  const int b = bh * 16 + bl, p = j0 + pi, pid = tid & 255;

  for (int i = tid; i < 4096; i += 512)
    gd[i] = gateG[(size_t)(bh * 16 + (i & 15)) * 256 + (i >> 4)];
  __syncthreads();

  // gate dot: K-half [h*128, h*128+128), gate broadcast from LDS
  double s0 = 0, s1 = 0, s2 = 0, s3 = 0, s4 = 0, s5 = 0, s6 = 0, s7 = 0;
  {
    const int k0 = h * 128;
    const float* wg = W_gate + (size_t)k0 * PP + p;
    const double* gq = gd + k0 * 16 + bl;
    for (int k = 0; k < 128; k += 8) {
      s0 += gq[(k + 0) * 16] * (double)wg[(size_t)(k + 0) * PP];
      s1 += gq[(k + 1) * 16] * (double)wg[(size_t)(k + 1) * PP];
      s2 += gq[(k + 2) * 16] * (double)wg[(size_t)(k + 2) * PP];
      s3 += gq[(k + 3) * 16] * (double)wg[(size_t)(k + 3) * PP];
      s4 += gq[(k + 4) * 16] * (double)wg[(size_t)(k + 4) * PP];
      s5 += gq[(k + 5) * 16] * (double)wg[(size_t)(k + 5) * PP];
      s6 += gq[(k + 6) * 16] * (double)wg[(size_t)(k + 6) * PP];
      s7 += gq[(k + 7) * 16] * (double)wg[(size_t)(k + 7) * PP];
    }
  }
  double vg = ((s0 + s1) + (s2 + s3)) + ((s4 + s5) + (s6 + s7));

  // rec: sparse rows, this K-half takes list entries i = h (mod 2)
  const int cnt = cntG[b];
  const u16* lst = listG + (size_t)b * PP;
  double v0 = 0, v1 = 0, v2 = 0, v3 = 0, v4 = 0, v5 = 0, v6 = 0, v7 = 0;
  int i = h;
  for (; i + 16 <= cnt; i += 16) {
    const int r0 = lst[i], r1 = lst[i + 2], r2 = lst[i + 4], r3 = lst[i + 6],
              r4 = lst[i + 8], r5 = lst[i + 10], r6 = lst[i + 12],
              r7 = lst[i + 14];
    v0 += (double)W_rec[(size_t)r0 * PP + p];
    v1 += (double)W_rec[(size_t)r1 * PP + p];
    v2 += (double)W_rec[(size_t)r2 * PP + p];
    v3 += (double)W_rec[(size_t)r3 * PP + p];
    v4 += (double)W_rec[(size_t)r4 * PP + p];
    v5 += (double)W_rec[(size_t)r5 * PP + p];
    v6 += (double)W_rec[(size_t)r6 * PP + p];
    v7 += (double)W_rec[(size_t)r7 * PP + p];
  }
  double vr = ((v0 + v1) + (v2 + v3)) + ((v4 + v5) + (v6 + v7));
  for (; i < cnt; i += 2) vr += (double)W_rec[(size_t)lst[i] * PP + p];

  if (h) {
    vgp[pid] = vg;
    vrp[pid] = vr;
  }
  __syncthreads();
  if (!h) {
    const double cur = (vg + vgp[pid]) + 0.1 * (vr + vrp[pid]);
    const double so = (double)((mask_rd[b * NG + g] >> pi) & 1);
    const size_t idx = (size_t)b * PP + p;
    const double mv = 0.9 * memD[idx] * (1.0 - so) + cur;
    const double sv = (mv - 1.0 > 0.0) ? 1.0 : 0.0;
    memD[idx] = mv;
    if (accum) rate[idx] += (float)sv;
    unsigned long long bal = __ballot(sv > 0.5);
    const int lane = tid & 63;
    if ((lane & 15) == 0)
      mask_wr[b * NG + g] = (u16)((bal >> (16 * (lane >> 4))) & 0xFFFFull);
  }
}

// ---- theta: 5 steps + compaction + a=tanh(spk@W_fb) + gamma/gate ----
// one block per batch, 1024 threads (4-way K-split on the gathers).
__global__ __launch_bounds__(1024) void k_theta(
    double* __restrict__ ring, double* __restrict__ gamma_g,
    double* __restrict__ a_g, double* __restrict__ gateG,
    const u16* __restrict__ spk_mask, u16* __restrict__ listG,
    int* __restrict__ cntG, const float* __restrict__ theta0,
    const float* __restrict__ omega, const float* __restrict__ W_ro,
    const float* __restrict__ W_fb, const double* __restrict__ gpartI,
    int k2) {
  const int b = blockIdx.x, tid = threadIdx.x;
  const int j = tid & 255, q = tid >> 8;
  const int lane = tid & 63, wid = tid >> 6;
  __shared__ double th[256];
  __shared__ double red[16];
  __shared__ double qpart[3 * 256];
  __shared__ int pc[NG], sc[NG];
  __shared__ u16 m_l[NG];
  __shared__ u16 list_l[PP];

  const int s0 = 5 * k2 + 1, s1 = 5 * k2 + 5;
  double new_a = 0.0;
  int total = 0;

  if (k2 > 0) {
    // compact spike mask -> sorted pixel list
    if (tid < NG) {
      m_l[tid] = spk_mask[b * NG + tid];
      pc[tid] = __popc((unsigned int)m_l[tid]);
      sc[tid] = pc[tid];
    }
    __syncthreads();
    for (int d = 1; d < NG; d <<= 1) {
      int v = 0;
      if (tid < NG) v = sc[tid] + ((tid >= d) ? sc[tid - d] : 0);
      __syncthreads();
      if (tid < NG) sc[tid] = v;
      __syncthreads();
    }
    total = sc[NG - 1];
    if (tid < NG) {
      int off = sc[tid] - pc[tid];
      unsigned int m = m_l[tid];
      while (m) {
        int bit = __builtin_ctz(m);
        m &= m - 1;
        list_l[off++] = (u16)(tid * 16 + bit);
      }
    }
    __syncthreads();
    for (int i = tid; i < total; i += 1024) listG[(size_t)b * PP + i] = list_l[i];
    if (tid == 0) cntG[b] = total;
    // a = tanh(spk @ W_fb): 4-way K-split x 8 streams
    double c0 = 0, c1 = 0, c2 = 0, c3 = 0, c4 = 0, c5 = 0, c6 = 0, c7 = 0;
    int i = q;
    for (; i + 32 <= total; i += 32) {
      c0 += (double)W_fb[(size_t)list_l[i + 0] * NN + j];
      c1 += (double)W_fb[(size_t)list_l[i + 4] * NN + j];
      c2 += (double)W_fb[(size_t)list_l[i + 8] * NN + j];
      c3 += (double)W_fb[(size_t)list_l[i + 12] * NN + j];
      c4 += (double)W_fb[(size_t)list_l[i + 16] * NN + j];
      c5 += (double)W_fb[(size_t)list_l[i + 20] * NN + j];
      c6 += (double)W_fb[(size_t)list_l[i + 24] * NN + j];
      c7 += (double)W_fb[(size_t)list_l[i + 28] * NN + j];
    }
    double acc = ((c0 + c1) + (c2 + c3)) + ((c4 + c5) + (c6 + c7));
    for (; i < total; i += 4) acc += (double)W_fb[(size_t)list_l[i] * NN + j];
    if (q) qpart[(q - 1) * 256 + j] = acc;
    __syncthreads();
    if (!q) new_a = tanh(acc + qpart[j] + qpart[256 + j] + qpart[512 + j]);
    __syncthreads();
  }

  double t = 0.0, aj = 0.0, gm = 0.0, om = 0.0;
  if (!q) {
    om = (double)omega[j];
    if (k2 == 0) {
      double s = 0.0;
      for (int c6 = 0; c6 < 6; ++c6) s += gpartI[((size_t)b * 6 + c6) * 256 + j];
      gm = tanh(s);
      t = (double)theta0[b * NN + j];
      ring[0 * BB * NN + b * NN + j] = t;
      if (tid == 0) cntG[b] = 0;
    } else {
      t = ring[((s0 - 1) & (RING - 1)) * BB * NN + b * NN + j];
      aj = a_g[b * NN + j];
      gm = gamma_g[b * NN + j];
    }
  }

  for (int s = s0; s <= s1; ++s) {
    if (!q && k2 > 0 && s == s0 + 1) {
      aj = new_a;  // step s0 uses the OLD a
      a_g[b * NN + j] = aj;
    }
    double sn = 0.0, cs = 0.0;
    if (!q) sincos(t, &sn, &cs);
    double r0 = sn, r1 = cs, r2 = aj * sn, r3 = aj * cs;
#pragma unroll
    for (int o = 32; o; o >>= 1) {
      r0 += __shfl_down(r0, o);
      r1 += __shfl_down(r1, o);
      r2 += __shfl_down(r2, o);
      r3 += __shfl_down(r3, o);
    }
    if (lane == 0 && wid < 4) {
      red[wid * 4 + 0] = r0;
      red[wid * 4 + 1] = r1;
      red[wid * 4 + 2] = r2;
      red[wid * 4 + 3] = r3;
    }
    __syncthreads();
    double S = red[0] + red[4] + red[8] + red[12];
    double C = red[1] + red[5] + red[9] + red[13];
    double AS = red[2] + red[6] + red[10] + red[14];
    double AC = red[3] + red[7] + red[11] + red[15];
    __syncthreads();
    if (!q) {
      double base = cs * S - sn * C;
      double wgt = 0.5 * (cs * aj * AS - sn * aj * AC);
      t = t + 0.1 * (om + (1.0 / 256.0) * (base + wgt) + 0.5 * gm);
      ring[(s & (RING - 1)) * BB * NN + b * NN + j] = t;
    }
  }
  if (!q) th[j] = t;
  __syncthreads();
  // gamma = tanh(theta @ W_ro): 4-way K-split x 8 streams
  {
    double c0 = 0, c1 = 0, c2 = 0, c3 = 0, c4 = 0, c5 = 0, c6 = 0, c7 = 0;
    const float* wp = W_ro + j;
    const int i0 = q * 64;
    for (int i = 0; i < 64; i += 8) {
      c0 += th[i0 + i + 0] * (double)wp[(size_t)(i0 + i + 0) * NN];
      c1 += th[i0 + i + 1] * (double)wp[(size_t)(i0 + i + 1) * NN];
      c2 += th[i0 + i + 2] * (double)wp[(size_t)(i0 + i + 2) * NN];
      c3 += th[i0 + i + 3] * (double)wp[(size_t)(i0 + i + 3) * NN];
      c4 += th[i0 + i + 4] * (double)wp[(size_t)(i0 + i + 4) * NN];
      c5 += th[i0 + i + 5] * (double)wp[(size_t)(i0 + i + 5) * NN];
      c6 += th[i0 + i + 6] * (double)wp[(size_t)(i0 + i + 6) * NN];
      c7 += th[i0 + i + 7] * (double)wp[(size_t)(i0 + i + 7) * NN];
    }
    double acc = ((c0 + c1) + (c2 + c3)) + ((c4 + c5) + (c6 + c7));
    if (q) qpart[(q - 1) * 256 + j] = acc;
    __syncthreads();
    if (!q) {
      double gnew = tanh(acc + qpart[j] + qpart[256 + j] + qpart[512 + j]);
      gamma_g[b * NN + j] = gnew;
      int sd = s1 - 11;
      if (sd < 0) sd = 0;
      double dly = ring[(sd & (RING - 1)) * BB * NN + b * NN + j];
      double gt = gnew * 0.5 * (1.0 + cos(t - dly));
      gateG[(size_t)b * 256 + j] = gt;
    }
  }
}

// ---- classifier ----
__global__ __launch_bounds__(256) void k_cls(const float* __restrict__ rate,
                                             const float* __restrict__ Wcls,
                                             const float* __restrict__ bcls,
                                             float* __restrict__ out) {
  const int b = blockIdx.x, t = threadIdx.x;
  double acc[10];
#pragma unroll
  for (int c = 0; c < 10; ++c) acc[c] = 0.0;
  for (int p = t; p < PP; p += 256) {
    double r = (double)rate[(size_t)b * PP + p] / 30.0;
#pragma unroll
    for (int c = 0; c < 10; ++c) acc[c] += r * (double)Wcls[(size_t)p * 10 + c];
  }
  __shared__ double sh[10][256];
#pragma unroll
  for (int c = 0; c < 10; ++c) sh[c][t] = acc[c];
  __syncthreads();
  for (int off = 128; off; off >>= 1) {
    if (t < off)
#pragma unroll
      for (int c = 0; c < 10; ++c) sh[c][t] += sh[c][t + off];
    __syncthreads();
  }
  if (t < 10) out[b * 10 + t] = (float)(sh[t][0] + (double)bcls[t]);
}

extern "C" void kernel_launch(void* const* d_in, const int* in_sizes, int n_in,
                              void* d_out, int out_size, void* d_ws,
                              size_t ws_size, hipStream_t stream) {
  const float* x = (const float*)d_in[0];
  const float* theta0 = (const float*)d_in[1];
  const float* W_init = (const float*)d_in[2];
  const float* omega = (const float*)d_in[3];
  const float* W_ro = (const float*)d_in[4];
  const float* W_gate = (const float*)d_in[5];
  const float* W_rec = (const float*)d_in[6];
  const float* W_fb = (const float*)d_in[7];
  const float* W_cls = (const float*)d_in[8];
  const float* b_cls = (const float*)d_in[9];

  char* w = (char*)d_ws;
  size_t off = 0;
  auto alloc = [&](size_t sz) -> void* {
    void* p = w + off;
    off = (off + sz + 255) & ~(size_t)255;
    return p;
  };
  double* ring = (double*)alloc((size_t)RING * BB * NN * 8);
  double* gamma = (double*)alloc((size_t)BB * NN * 8);
  double* a_g = (double*)alloc((size_t)BB * NN * 8);
  double* gateG = (double*)alloc((size_t)BB * NN * 8);
  double* memD = (double*)alloc((size_t)BB * PP * 8);
  float* rate = (float*)alloc((size_t)BB * PP * 4);
  u16* maskA = (u16*)alloc((size_t)BB * NG * 2);
  u16* maskB = (u16*)alloc((size_t)BB * NG * 2);
  u16* listG = (u16*)alloc((size_t)BB * PP * 2);
  int* cntG = (int*)alloc((size_t)BB * 4);
  double* gpartI = (double*)alloc((size_t)BB * 6 * 256 * 8);

  k_init<<<224, 512, 0, stream>>>(x, W_init, gpartI, memD, a_g, rate, maskA,
                                  maskB);
  k_theta<<<32, 1024, 0, stream>>>(ring, gamma, a_g, gateG, maskB, listG, cntG,
                                   theta0, omega, W_ro, W_fb, gpartI, 0);
  for (int k = 1; k < 40; ++k) {
    const u16* mrd = (k & 1) ? maskA : maskB;  // k=1 reads zeros
    u16* mwr = (k & 1) ? maskB : maskA;
    k_spike<<<dim3(192, 2), 512, 0, stream>>>(mrd, mwr, memD, gateG, W_rec,
                                              W_gate, listG, cntG, rate,
                                              (k >= 10) ? 1 : 0);
    k_theta<<<32, 1024, 0, stream>>>(ring, gamma, a_g, gateG, mwr, listG, cntG,
                                     theta0, omega, W_ro, W_fb, gpartI, k);
  }
  k_cls<<<32, 256, 0, stream>>>(rate, W_cls, b_cls, (float*)d_out);
}